// Round 8
// baseline (381.628 us; speedup 1.0000x reference)
//
#include <hip/hip_runtime.h>

#define NB   256            // batch
#define NSQ  64             // squares used (rows 3..66)
#define NH   1024           // hidden
#define ND   256            // proj dim
#define NV   1858           // moves
#define N_   512            // fp|tp concat
#define NKT  32             // K/32 k-steps

typedef __attribute__((ext_vector_type(4))) float f32x4;
typedef __attribute__((ext_vector_type(8))) short bf16x8;
typedef __attribute__((ext_vector_type(8))) unsigned short u16x8;

__device__ __forceinline__ unsigned short bf16_rne(float x) {
    unsigned u = __float_as_uint(x);
    unsigned r = u + 0x7fffu + ((u >> 16) & 1u);
    return (unsigned short)(r >> 16);
}

__device__ __forceinline__ void gload16(const void* g, void* l) {
    __builtin_amdgcn_global_load_lds(
        (const __attribute__((address_space(1))) unsigned int*)g,
        (__attribute__((address_space(3))) unsigned int*)l, 16, 0, 0);
}

// ---- cast [Wf;Wt] into permuted split-bf16 tiles (4 MB total) ----
// tile = rt(128-rowblock)*32 + kt, 8 KB interior: [g 0..7][s 0..3][r 0..15]*16B
__global__ __launch_bounds__(256) void cast_W_kernel(
    const float* __restrict__ Wf, const float* __restrict__ Wt,
    char* __restrict__ Whi, char* __restrict__ Wlo) {
    int bid = blockIdx.x;             // 0..255
    int tid = threadIdx.x;
    int o = tid * 16;
    int g_l = o >> 10;
    int w = o & 1023;
    int s = w >> 8;
    int r = (w >> 4) & 15;
    int nrb = bid >> 5, kt = bid & 31;
    int n = nrb * 64 + g_l * 16 + r;
    int k = kt * 32 + s * 8;
    const float* src = ((n < ND) ? (Wf + (size_t)n * NH) : (Wt + (size_t)(n - ND) * NH)) + k;
    size_t outb = ((size_t)((nrb >> 1) * 32 + kt) << 13) + ((nrb & 1) << 12) + o;
    float4 v0 = ((const float4*)src)[0];
    float4 v1 = ((const float4*)src)[1];
    float vv[8] = {v0.x, v0.y, v0.z, v0.w, v1.x, v1.y, v1.z, v1.w};
    u16x8 h, l;
#pragma unroll
    for (int j = 0; j < 8; ++j) {
        unsigned short hb = bf16_rne(vv[j]);
        float hf = __uint_as_float((unsigned)hb << 16);
        h[j] = hb;
        l[j] = bf16_rne(vv[j] - hf);
    }
    *(u16x8*)(Whi + outb) = h;
    *(u16x8*)(Wlo + outb) = l;
}

// ---- gp[b][d] = hidden[b][0][:] . Wg[d][:] + bg[d], fp32 exact ----
__global__ __launch_bounds__(1024) void gp_kernel(
    const float* __restrict__ hid, const float* __restrict__ Wg,
    const float* __restrict__ bg, float* __restrict__ gp) {
    __shared__ float h[NH];
    int b = blockIdx.x;
    int tid = threadIdx.x;
    if (tid < 256) ((float4*)h)[tid] = ((const float4*)(hid + (size_t)b * 128 * NH))[tid];
    __syncthreads();
    int wave = tid >> 6, lane = tid & 63;
    const float4* hs = (const float4*)h;
    for (int dd = 0; dd < 16; ++dd) {
        int d = wave * 16 + dd;
        const float4* wrow = (const float4*)(Wg + (size_t)d * NH);
        float acc = 0.f;
#pragma unroll
        for (int p = 0; p < 4; ++p) {
            float4 w = wrow[p * 64 + lane];
            float4 x = hs[p * 64 + lane];
            acc += w.x * x.x + w.y * x.y + w.z * x.z + w.w * x.w;
        }
#pragma unroll
        for (int o = 32; o > 0; o >>= 1) acc += __shfl_xor(acc, o, 64);
        if (lane == 0) gp[(size_t)b * ND + d] = acc + bg[d];
    }
}

// ---- FUSED: per-b {A-cast + split-bf16 GEMM (64x512) + gather/relu-dot} ----
// 512 thr = 8 waves, each wave: 64 rows x 64-col strip, acc[4][4].
// LDS 144 KB: Bbuf dbuf 2x64KB @0; A(hi4K|lo4K) dbuf 2x8KB @131072.
__global__ __launch_bounds__(512) void fused_kernel(
    const float* __restrict__ hid,
    const char* __restrict__ Whi, const char* __restrict__ Wlo,
    const float* __restrict__ bfv, const float* __restrict__ btv,
    const float* __restrict__ gp, const float* __restrict__ promo,
    const float* __restrict__ Wsv, const float* __restrict__ bsv,
    const int* __restrict__ from_sqs, const int* __restrict__ to_sqs,
    const int* __restrict__ ptypes, float* __restrict__ out) {
    __shared__ __align__(16) char lds[147456];
    const int tid = threadIdx.x;
    const int lane = tid & 63, wv = tid >> 6;
    const int fr = lane & 15, kh = lane >> 4;
    const int b = blockIdx.x;

    // A reg-load: lane covers (row = tid>>3, 4-float chunk = tid&7) of 64x32 slice
    const int arow = tid >> 3, ak4 = tid & 7;
    const float* asrc = hid + (size_t)(b * 128 + 3 + arow) * NH + ak4 * 4;
    // A LDS write slot (hi; lo at +4096), within 8KB parity buffer @131072
    const int awoff = 131072 + (arow >> 4) * 1024 + (ak4 >> 1) * 256 +
                      (arow & 15) * 16 + (ak4 & 1) * 8;

    // B frag base: n = wv*64 + j*16 + fr -> rt=wv>>1, g=(wv&1)*4+j
    const int bbase = (wv >> 1) * 8192 + (wv & 1) * 4096 + kh * 256 + fr * 16;
    // A frag base (hi; lo +4096): + p*8192 + i*1024
    const int abase = 131072 + kh * 256 + fr * 16;

#define BSTG(kt, p)                                                              \
    do {                                                                         \
        _Pragma("unroll") for (int l = 0; l < 4; ++l) {                          \
            gload16(Whi + (((size_t)(l * NKT + (kt))) << 13) + tid * 16,         \
                    lds + (p) * 65536 + l * 8192 + tid * 16);                    \
            gload16(Wlo + (((size_t)(l * NKT + (kt))) << 13) + tid * 16,         \
                    lds + (p) * 65536 + 32768 + l * 8192 + tid * 16);            \
        }                                                                        \
    } while (0)

    f32x4 acc[4][4] = {};

    // prologue: issue order must be B0(8), A0(1), B1(8), A1(1) for vmcnt math
    BSTG(0, 0);
    __builtin_amdgcn_sched_barrier(0);
    float4 a_cur = *(const float4*)(asrc);
    __builtin_amdgcn_sched_barrier(0);
    BSTG(1, 1);
    __builtin_amdgcn_sched_barrier(0);
    float4 a_nxt = *(const float4*)(asrc + 32);
    __builtin_amdgcn_sched_barrier(0);

#pragma unroll 1
    for (int t = 0; t < NKT; ++t) {
        const int p = t & 1;
        // convert A(t) -> split bf16, ds_write into parity buffer
        ushort4 h4, l4;
        {
            h4.x = bf16_rne(a_cur.x);
            l4.x = bf16_rne(a_cur.x - __uint_as_float((unsigned)h4.x << 16));
            h4.y = bf16_rne(a_cur.y);
            l4.y = bf16_rne(a_cur.y - __uint_as_float((unsigned)h4.y << 16));
            h4.z = bf16_rne(a_cur.z);
            l4.z = bf16_rne(a_cur.z - __uint_as_float((unsigned)h4.z << 16));
            h4.w = bf16_rne(a_cur.w);
            l4.w = bf16_rne(a_cur.w - __uint_as_float((unsigned)h4.w << 16));
        }
        *(ushort4*)(lds + awoff + p * 8192) = h4;
        *(ushort4*)(lds + awoff + p * 8192 + 4096) = l4;
        // B(t)+A(t) complete (9 newest = B(t+1)+A(t+1) stay in flight)
        asm volatile("s_waitcnt vmcnt(9)" ::: "memory");
        asm volatile("s_waitcnt lgkmcnt(0)" ::: "memory");
        asm volatile("s_barrier" ::: "memory");

        const char* bb = lds + p * 65536;
        bf16x8 bh[4], bl[4];
#pragma unroll
        for (int j = 0; j < 4; ++j) {
            bh[j] = *(const bf16x8*)(bb + bbase + j * 1024);
            bl[j] = *(const bf16x8*)(bb + bbase + 32768 + j * 1024);
        }
        __builtin_amdgcn_s_setprio(1);
#pragma unroll
        for (int i = 0; i < 4; ++i) {
            bf16x8 ah = *(const bf16x8*)(lds + abase + p * 8192 + i * 1024);
            bf16x8 al = *(const bf16x8*)(lds + abase + p * 8192 + 4096 + i * 1024);
#pragma unroll
            for (int j = 0; j < 4; ++j) {
                acc[i][j] = __builtin_amdgcn_mfma_f32_16x16x32_bf16(ah, bh[j], acc[i][j], 0, 0, 0);
                acc[i][j] = __builtin_amdgcn_mfma_f32_16x16x32_bf16(ah, bl[j], acc[i][j], 0, 0, 0);
                acc[i][j] = __builtin_amdgcn_mfma_f32_16x16x32_bf16(al, bh[j], acc[i][j], 0, 0, 0);
            }
        }
        __builtin_amdgcn_s_setprio(0);
        asm volatile("s_barrier" ::: "memory");   // all waves done reading buf p

        const int ktn = (t + 2) & (NKT - 1);      // wraps to dummy re-stage at end
        BSTG(ktn, p);
        __builtin_amdgcn_sched_barrier(0);
        a_cur = a_nxt;
        a_nxt = *(const float4*)(asrc + ktn * 32);
        __builtin_amdgcn_sched_barrier(0);
    }

    // ---- epilogue: C (+bias) -> LDS, then gather + relu-dot ----
    asm volatile("s_waitcnt vmcnt(0) lgkmcnt(0)" ::: "memory");
    asm volatile("s_barrier" ::: "memory");

    float* cb = (float*)lds;                      // [64][512] fp32 = 128 KB
#pragma unroll
    for (int j = 0; j < 4; ++j) {
        int col = wv * 64 + j * 16 + fr;
        float bv = (col < ND) ? bfv[col] : btv[col - ND];
#pragma unroll
        for (int i = 0; i < 4; ++i) {
            int row = i * 16 + kh * 4;
#pragma unroll
            for (int r = 0; r < 4; ++r)
                cb[(row + r) * N_ + col] = acc[i][j][r] + bv;
        }
    }
    float* gpl = (float*)(lds + 131072);          // 1 KB
    float* wsl = (float*)(lds + 132096);          // 1 KB
    float* pl  = (float*)(lds + 133120);          // 5 KB
    if (tid < 64) ((float4*)gpl)[tid] = ((const float4*)(gp + (size_t)b * ND))[tid];
    else if (tid < 128) ((float4*)wsl)[tid - 64] = ((const float4*)Wsv)[tid - 64];
    else if (tid < 448) ((float4*)pl)[tid - 128] = ((const float4*)promo)[tid - 128];
    asm volatile("s_waitcnt lgkmcnt(0)" ::: "memory");
    asm volatile("s_barrier" ::: "memory");

    const float4* cb4 = (const float4*)lds;
    const float4* pl4 = (const float4*)pl;
    float4 g4 = ((const float4*)gpl)[lane];
    float4 w4 = ((const float4*)wsl)[lane];
    float bias0 = bsv[0];
    for (int v = wv; v < NV; v += 8) {
        int sf = from_sqs[v];
        int st = to_sqs[v];
        int pt = ptypes[v];
        float4 a  = cb4[sf * 128 + lane];         // fp cols 0..255
        float4 t4 = cb4[st * 128 + 64 + lane];    // tp cols 256..511
        float4 pp = pl4[pt * 64 + lane];
        float c0 = a.x * t4.x + g4.x + pp.x;
        float c1 = a.y * t4.y + g4.y + pp.y;
        float c2 = a.z * t4.z + g4.z + pp.z;
        float c3 = a.w * t4.w + g4.w + pp.w;
        float s = fmaxf(c0, 0.f) * w4.x + fmaxf(c1, 0.f) * w4.y +
                  fmaxf(c2, 0.f) * w4.z + fmaxf(c3, 0.f) * w4.w;
#pragma unroll
        for (int o = 32; o > 0; o >>= 1) s += __shfl_xor(s, o, 64);
        if (lane == 0) out[(size_t)b * NV + v] = s + bias0;
    }
#undef BSTG
}

extern "C" void kernel_launch(void* const* d_in, const int* in_sizes, int n_in,
                              void* d_out, int out_size, void* d_ws, size_t ws_size,
                              hipStream_t stream) {
    (void)in_sizes; (void)n_in; (void)out_size; (void)ws_size;
    const float* hid   = (const float*)d_in[0];
    const float* Wf    = (const float*)d_in[1];
    const float* bfv   = (const float*)d_in[2];
    const float* Wt    = (const float*)d_in[3];
    const float* btv   = (const float*)d_in[4];
    const float* Wg    = (const float*)d_in[5];
    const float* bgv   = (const float*)d_in[6];
    const float* promo = (const float*)d_in[7];
    const float* Wsv   = (const float*)d_in[8];
    const float* bsv   = (const float*)d_in[9];
    const int* from_sqs = (const int*)d_in[10];
    const int* to_sqs   = (const int*)d_in[11];
    const int* ptypes   = (const int*)d_in[12];
    float* out = (float*)d_out;

    char* ws = (char*)d_ws;
    // layout: Whi 1MiB | Wlo 1MiB | gp 256KiB
    char* Whi = ws;
    char* Wlo = ws + 1048576;
    float* gp = (float*)(ws + 2097152);

    cast_W_kernel<<<256, 256, 0, stream>>>(Wf, Wt, Whi, Wlo);
    gp_kernel<<<256, 1024, 0, stream>>>(hid, Wg, bgv, gp);
    fused_kernel<<<256, 512, 0, stream>>>(hid, Whi, Wlo, bfv, btv, gp,
                                          promo, Wsv, bsv,
                                          from_sqs, to_sqs, ptypes, out);
}

// Round 9
// 328.661 us; speedup vs baseline: 1.1612x; 1.1612x over previous
//
#include <hip/hip_runtime.h>

#define NB   256            // batch
#define NSQ  64             // squares used (rows 3..66)
#define NH   1024           // hidden
#define ND   256            // proj dim
#define NV   1858           // moves
#define M_   (NB * NSQ)     // 16384 GEMM rows
#define N_   512            // fp|tp concat
#define NKT  32             // K/32 k-steps

typedef __attribute__((ext_vector_type(4))) float f32x4;
typedef __attribute__((ext_vector_type(8))) short bf16x8;
typedef __attribute__((ext_vector_type(8))) unsigned short u16x8;

__device__ __forceinline__ unsigned short bf16_rne(float x) {
    unsigned u = __float_as_uint(x);
    unsigned r = u + 0x7fffu + ((u >> 16) & 1u);
    return (unsigned short)(r >> 16);
}

__device__ __forceinline__ void gload16(const void* g, void* l) {
    __builtin_amdgcn_global_load_lds(
        (const __attribute__((address_space(1))) unsigned int*)g,
        (__attribute__((address_space(3))) unsigned int*)l, 16, 0, 0);
}

__device__ __forceinline__ void split8(const float4 a, const float4 b,
                                       u16x8& hi, u16x8& lo) {
    float vv[8] = {a.x, a.y, a.z, a.w, b.x, b.y, b.z, b.w};
#pragma unroll
    for (int j = 0; j < 8; ++j) {
        unsigned short hb = bf16_rne(vv[j]);
        hi[j] = hb;
        lo[j] = bf16_rne(vv[j] - __uint_as_float((unsigned)hb << 16));
    }
}

// ---- cast [Wf;Wt] into permuted split-bf16 tiles (4 MB total) ----
// tile = rt(128-rowblock)*32 + kt, 8 KB interior: [g 0..7][s 0..3][r 0..15]*16B
__global__ __launch_bounds__(256) void cast_W_kernel(
    const float* __restrict__ Wf, const float* __restrict__ Wt,
    char* __restrict__ Whi, char* __restrict__ Wlo) {
    int bid = blockIdx.x;             // 0..255
    int tid = threadIdx.x;
    int o = tid * 16;
    int g_l = o >> 10;
    int w = o & 1023;
    int s = w >> 8;
    int r = (w >> 4) & 15;
    int nrb = bid >> 5, kt = bid & 31;
    int n = nrb * 64 + g_l * 16 + r;
    int k = kt * 32 + s * 8;
    const float* src = ((n < ND) ? (Wf + (size_t)n * NH) : (Wt + (size_t)(n - ND) * NH)) + k;
    size_t outb = ((size_t)((nrb >> 1) * 32 + kt) << 13) + ((nrb & 1) << 12) + o;
    float4 v0 = ((const float4*)src)[0];
    float4 v1 = ((const float4*)src)[1];
    u16x8 h, l;
    split8(v0, v1, h, l);
    *(u16x8*)(Whi + outb) = h;
    *(u16x8*)(Wlo + outb) = l;
}

// ---- gp[b][d] = hidden[b][0][:] . Wg[d][:] + bg[d], fp32 exact ----
__global__ __launch_bounds__(1024) void gp_kernel(
    const float* __restrict__ hid, const float* __restrict__ Wg,
    const float* __restrict__ bg, float* __restrict__ gp) {
    __shared__ float h[NH];
    int b = blockIdx.x;
    int tid = threadIdx.x;
    if (tid < 256) ((float4*)h)[tid] = ((const float4*)(hid + (size_t)b * 128 * NH))[tid];
    __syncthreads();
    int wave = tid >> 6, lane = tid & 63;
    const float4* hs = (const float4*)h;
    for (int dd = 0; dd < 16; ++dd) {
        int d = wave * 16 + dd;
        const float4* wrow = (const float4*)(Wg + (size_t)d * NH);
        float acc = 0.f;
#pragma unroll
        for (int p = 0; p < 4; ++p) {
            float4 w = wrow[p * 64 + lane];
            float4 x = hs[p * 64 + lane];
            acc += w.x * x.x + w.y * x.y + w.z * x.z + w.w * x.w;
        }
#pragma unroll
        for (int o = 32; o > 0; o >>= 1) acc += __shfl_xor(acc, o, 64);
        if (lane == 0) gp[(size_t)b * ND + d] = acc + bg[d];
    }
}

// ---- fused A-cast + 3-term split-bf16 GEMM: C = A*W^T + bias ----
// 128x128 tile, BK=32, 4 waves, m97 2-barrier structure (__syncthreads,
// compiler-scheduled). A: fp32 reg-load -> in-reg split -> ds_write into
// permuted layout. B: global_load_lds from pre-cast permuted Whi/Wlo.
__global__ __launch_bounds__(256) void gemm3f_kernel(
    const float* __restrict__ hid,
    const char* __restrict__ Whi, const char* __restrict__ Wlo,
    const float* __restrict__ bfv, const float* __restrict__ btv,
    float* __restrict__ C) {
    __shared__ __align__(16) char lA[16384];   // Ahi 8K | Alo 8K (permuted)
    __shared__ __align__(16) char lB[16384];   // Bhi 8K | Blo 8K (permuted)
    int tid = threadIdx.x;
    int lane = tid & 63, wv = tid >> 6;
    int wgid = (blockIdx.x & 7) * 64 + (blockIdx.x >> 3);   // XCD-chunked, 512%8==0
    int nt = wgid & 3;        // 4 n-tiles of 128
    int mt = wgid >> 2;       // 128 m-tiles of 128
    int wm = (wv >> 1) * 64, wn = (wv & 1) * 64;
    int fr = lane & 15, kh = lane >> 4;

    // A: thread covers row r = tid>>1 (0..127), k-half h = tid&1 (16 floats)
    int r = tid >> 1, h = tid & 1;
    const float* asrc = hid +
        (size_t)((2 * mt + (r >> 6)) * 128 + 3 + (r & 63)) * NH + h * 16;
    // permuted A-tile byte offset: g=r>>4, s=h*2 (and +1 at +256), rr=r&15
    int awb = (r >> 4) * 1024 + h * 512 + (r & 15) * 16;

    const char* bsrch = Whi + ((size_t)(nt * NKT) << 13) + tid * 16;
    const char* bsrcl = Wlo + ((size_t)(nt * NKT) << 13) + tid * 16;

    f32x4 acc[4][4] = {};
    float4 va0, va1, va2, va3, vn0, vn1, vn2, vn3;
    va0 = ((const float4*)asrc)[0];
    va1 = ((const float4*)asrc)[1];
    va2 = ((const float4*)asrc)[2];
    va3 = ((const float4*)asrc)[3];

    for (int kt = 0; kt < NKT; ++kt) {
        // stage B(kt): 4x global_load_lds (16B), linear LDS dest
        size_t tb = (size_t)kt << 13;
        gload16(bsrch + tb, lB + tid * 16);
        gload16(bsrch + tb + 4096, lB + 4096 + tid * 16);
        gload16(bsrcl + tb, lB + 8192 + tid * 16);
        gload16(bsrcl + tb + 4096, lB + 12288 + tid * 16);

        // convert A(kt) -> split bf16, ds_write (permuted, conflict-free)
        u16x8 h0, h1, l0, l1;
        split8(va0, va1, h0, l0);
        split8(va2, va3, h1, l1);
        *(u16x8*)(lA + awb) = h0;
        *(u16x8*)(lA + awb + 256) = h1;
        *(u16x8*)(lA + 8192 + awb) = l0;
        *(u16x8*)(lA + 8192 + awb + 256) = l1;
        __syncthreads();

        // reg-prefetch A(kt+1) during the MFMA phase
        int ktn = (kt + 1) & (NKT - 1);
        const float* an = asrc + ktn * 32;
        vn0 = ((const float4*)an)[0];
        vn1 = ((const float4*)an)[1];
        vn2 = ((const float4*)an)[2];
        vn3 = ((const float4*)an)[3];

        bf16x8 ah[4], al[4], bh[4], bl[4];
#pragma unroll
        for (int f = 0; f < 4; ++f) {
            int ea = (wm + f * 16) * 64 + kh * 256 + fr * 16;
            int eb = (wn + f * 16) * 64 + kh * 256 + fr * 16;
            ah[f] = *(const bf16x8*)(lA + ea);
            al[f] = *(const bf16x8*)(lA + 8192 + ea);
            bh[f] = *(const bf16x8*)(lB + eb);
            bl[f] = *(const bf16x8*)(lB + 8192 + eb);
        }
#pragma unroll
        for (int i = 0; i < 4; ++i)
#pragma unroll
            for (int j = 0; j < 4; ++j) {
                acc[i][j] = __builtin_amdgcn_mfma_f32_16x16x32_bf16(ah[i], bh[j], acc[i][j], 0, 0, 0);
                acc[i][j] = __builtin_amdgcn_mfma_f32_16x16x32_bf16(ah[i], bl[j], acc[i][j], 0, 0, 0);
                acc[i][j] = __builtin_amdgcn_mfma_f32_16x16x32_bf16(al[i], bh[j], acc[i][j], 0, 0, 0);
            }
        __syncthreads();
        va0 = vn0; va1 = vn1; va2 = vn2; va3 = vn3;
    }

    // ---- epilogue: bias + C write (same mapping as R4) ----
    const float* bias = (nt < 2) ? bfv : btv;
    int nb0 = nt * 128 - ((nt < 2) ? 0 : 256);
#pragma unroll
    for (int j = 0; j < 4; ++j) {
        int ncol = nt * 128 + wn + j * 16 + fr;
        float bv = bias[nb0 + wn + j * 16 + fr];
#pragma unroll
        for (int i = 0; i < 4; ++i) {
            int mrow = mt * 128 + wm + i * 16 + kh * 4;
#pragma unroll
            for (int rr = 0; rr < 4; ++rr) {
                C[(size_t)(mrow + rr) * N_ + ncol] = acc[i][j][rr] + bv;
            }
        }
    }
}

// ---- gather + relu-dot: out[b][v] ----
__global__ __launch_bounds__(1024) void out_kernel(
    const float* __restrict__ C, const float* __restrict__ gp,
    const float* __restrict__ promo_tab, const float* __restrict__ Wsv,
    const float* __restrict__ bsv,
    const int* __restrict__ from_sqs, const int* __restrict__ to_sqs,
    const int* __restrict__ ptypes, float* __restrict__ out) {
    __shared__ float cb[NSQ * N_];       // 128 KB: fp|tp rows of this b
    __shared__ float gpl[ND];
    __shared__ float wsl[ND];
    __shared__ float pl[5 * ND];
    __shared__ int fsq[NV], tsq[NV], pty[NV];
    int b = blockIdx.x;
    int tid = threadIdx.x;
    const float4* src = (const float4*)(C + (size_t)b * NSQ * N_);
    float4* dst = (float4*)cb;
#pragma unroll
    for (int i = 0; i < 8; ++i) dst[tid + i * 1024] = src[tid + i * 1024];
    if (tid < 64) ((float4*)gpl)[tid] = ((const float4*)(gp + (size_t)b * ND))[tid];
    else if (tid < 128) ((float4*)wsl)[tid - 64] = ((const float4*)Wsv)[tid - 64];
    else if (tid < 448) ((float4*)pl)[tid - 128] = ((const float4*)promo_tab)[tid - 128];
    for (int v = tid; v < NV; v += 1024) {
        fsq[v] = from_sqs[v];
        tsq[v] = to_sqs[v];
        pty[v] = ptypes[v];
    }
    __syncthreads();

    int wave = tid >> 6, lane = tid & 63;
    float bias0 = bsv[0];
    const float4* cb4 = (const float4*)cb;
    const float4* gp4 = (const float4*)gpl;
    const float4* ws4 = (const float4*)wsl;
    const float4* pl4 = (const float4*)pl;
    for (int v = wave; v < NV; v += 16) {
        int sf = fsq[v];
        int st = tsq[v];
        int p  = pty[v];
        float4 a = cb4[sf * 128 + lane];
        float4 t = cb4[st * 128 + 64 + lane];
        float4 g = gp4[lane];
        float4 pp = pl4[p * 64 + lane];
        float4 w = ws4[lane];
        float c0 = a.x * t.x + g.x + pp.x;
        float c1 = a.y * t.y + g.y + pp.y;
        float c2 = a.z * t.z + g.z + pp.z;
        float c3 = a.w * t.w + g.w + pp.w;
        float s = fmaxf(c0, 0.f) * w.x + fmaxf(c1, 0.f) * w.y +
                  fmaxf(c2, 0.f) * w.z + fmaxf(c3, 0.f) * w.w;
#pragma unroll
        for (int o = 32; o > 0; o >>= 1) s += __shfl_xor(s, o, 64);
        if (lane == 0) out[(size_t)b * NV + v] = s + bias0;
    }
}

extern "C" void kernel_launch(void* const* d_in, const int* in_sizes, int n_in,
                              void* d_out, int out_size, void* d_ws, size_t ws_size,
                              hipStream_t stream) {
    (void)in_sizes; (void)n_in; (void)out_size; (void)ws_size;
    const float* hid   = (const float*)d_in[0];
    const float* Wf    = (const float*)d_in[1];
    const float* bfv   = (const float*)d_in[2];
    const float* Wt    = (const float*)d_in[3];
    const float* btv   = (const float*)d_in[4];
    const float* Wg    = (const float*)d_in[5];
    const float* bgv   = (const float*)d_in[6];
    const float* promo = (const float*)d_in[7];
    const float* Wsv   = (const float*)d_in[8];
    const float* bsv   = (const float*)d_in[9];
    const int* from_sqs = (const int*)d_in[10];
    const int* to_sqs   = (const int*)d_in[11];
    const int* ptypes   = (const int*)d_in[12];
    float* out = (float*)d_out;

    char* ws = (char*)d_ws;
    // layout: Whi 1MiB | Wlo 1MiB | C 32MiB | gp 256KiB
    char* Whi = ws;
    char* Wlo = ws + 1048576;
    float* C  = (float*)(ws + 2097152);
    float* gp = (float*)(ws + 35651584);

    cast_W_kernel<<<256, 256, 0, stream>>>(Wf, Wt, Whi, Wlo);
    gp_kernel<<<256, 1024, 0, stream>>>(hid, Wg, bgv, gp);
    gemm3f_kernel<<<512, 256, 0, stream>>>(hid, Whi, Wlo, bfv, btv, C);
    out_kernel<<<256, 1024, 0, stream>>>(C, gp, promo, Wsv, bsv,
                                         from_sqs, to_sqs, ptypes, out);
}

// Round 12
// 320.937 us; speedup vs baseline: 1.1891x; 1.0241x over previous
//
#include <hip/hip_runtime.h>

#define NB   256            // batch
#define NSQ  64             // squares used (rows 3..66)
#define NH   1024           // hidden
#define ND   256            // proj dim
#define NV   1858           // moves
#define M_   (NB * NSQ)     // 16384 GEMM rows
#define N_   512            // fp|tp concat
#define NKT  32             // K/32 k-steps

typedef __attribute__((ext_vector_type(4))) float f32x4;
typedef __attribute__((ext_vector_type(8))) short bf16x8;
typedef __attribute__((ext_vector_type(8))) unsigned short u16x8;

__device__ __forceinline__ unsigned short bf16_rne(float x) {
    unsigned u = __float_as_uint(x);
    unsigned r = u + 0x7fffu + ((u >> 16) & 1u);
    return (unsigned short)(r >> 16);
}

__device__ __forceinline__ void gload16(const void* g, void* l) {
    __builtin_amdgcn_global_load_lds(
        (const __attribute__((address_space(1))) unsigned int*)g,
        (__attribute__((address_space(3))) unsigned int*)l, 16, 0, 0);
}

__device__ __forceinline__ void split8(const float4 a, const float4 b,
                                       u16x8& hi, u16x8& lo) {
    float vv[8] = {a.x, a.y, a.z, a.w, b.x, b.y, b.z, b.w};
#pragma unroll
    for (int j = 0; j < 8; ++j) {
        unsigned short hb = bf16_rne(vv[j]);
        hi[j] = hb;
        lo[j] = bf16_rne(vv[j] - __uint_as_float((unsigned)hb << 16));
    }
}

// ---- cast [Wf;Wt] into permuted split-bf16 tiles (4 MB total) ----
// tile = rt(128-rowblock)*32 + kt, 8 KB interior: [g 0..7][s 0..3][r 0..15]*16B
__global__ __launch_bounds__(256) void cast_W_kernel(
    const float* __restrict__ Wf, const float* __restrict__ Wt,
    char* __restrict__ Whi, char* __restrict__ Wlo) {
    int bid = blockIdx.x;             // 0..255
    int tid = threadIdx.x;
    int o = tid * 16;
    int g_l = o >> 10;
    int w = o & 1023;
    int s = w >> 8;
    int r = (w >> 4) & 15;
    int nrb = bid >> 5, kt = bid & 31;
    int n = nrb * 64 + g_l * 16 + r;
    int k = kt * 32 + s * 8;
    const float* src = ((n < ND) ? (Wf + (size_t)n * NH) : (Wt + (size_t)(n - ND) * NH)) + k;
    size_t outb = ((size_t)((nrb >> 1) * 32 + kt) << 13) + ((nrb & 1) << 12) + o;
    float4 v0 = ((const float4*)src)[0];
    float4 v1 = ((const float4*)src)[1];
    u16x8 h, l;
    split8(v0, v1, h, l);
    *(u16x8*)(Whi + outb) = h;
    *(u16x8*)(Wlo + outb) = l;
}

// ---- gp[b][d] = hidden[b][0][:] . Wg[d][:] + bg[d], fp32 exact ----
__global__ __launch_bounds__(1024) void gp_kernel(
    const float* __restrict__ hid, const float* __restrict__ Wg,
    const float* __restrict__ bg, float* __restrict__ gp) {
    __shared__ float h[NH];
    int b = blockIdx.x;
    int tid = threadIdx.x;
    if (tid < 256) ((float4*)h)[tid] = ((const float4*)(hid + (size_t)b * 128 * NH))[tid];
    __syncthreads();
    int wave = tid >> 6, lane = tid & 63;
    const float4* hs = (const float4*)h;
    for (int dd = 0; dd < 16; ++dd) {
        int d = wave * 16 + dd;
        const float4* wrow = (const float4*)(Wg + (size_t)d * NH);
        float acc = 0.f;
#pragma unroll
        for (int p = 0; p < 4; ++p) {
            float4 w = wrow[p * 64 + lane];
            float4 x = hs[p * 64 + lane];
            acc += w.x * x.x + w.y * x.y + w.z * x.z + w.w * x.w;
        }
#pragma unroll
        for (int o = 32; o > 0; o >>= 1) acc += __shfl_xor(acc, o, 64);
        if (lane == 0) gp[(size_t)b * ND + d] = acc + bg[d];
    }
}

// ---- fused A-cast + 3-term split-bf16 GEMM: C = A*W^T + bias ----
// 128x128 tile, BK=32, 4 waves. Double-buffered A and B (64 KB LDS),
// stage-early / consume-current / ONE __syncthreads per K-step:
// the barrier drain lands after loads had the whole step in flight.
__global__ __launch_bounds__(256) void gemm3f_kernel(
    const float* __restrict__ hid,
    const char* __restrict__ Whi, const char* __restrict__ Wlo,
    const float* __restrict__ bfv, const float* __restrict__ btv,
    float* __restrict__ C) {
    __shared__ __align__(16) char lA[32768];   // [p][Ahi 8K | Alo 8K]
    __shared__ __align__(16) char lB[32768];   // [p][Bhi 8K | Blo 8K]
    int tid = threadIdx.x;
    int lane = tid & 63, wv = tid >> 6;
    int wgid = (blockIdx.x & 7) * 64 + (blockIdx.x >> 3);   // XCD-chunked, 512%8==0
    int nt = wgid & 3;        // 4 n-tiles of 128
    int mt = wgid >> 2;       // 128 m-tiles of 128
    int fr = lane & 15, kh = lane >> 4;

    // A: thread covers row r = tid>>1 (0..127), k-half h = tid&1 (16 floats)
    int r = tid >> 1, h = tid & 1;
    const float* asrc = hid +
        (size_t)((2 * mt + (r >> 6)) * 128 + 3 + (r & 63)) * NH + h * 16;
    // permuted A-tile byte offset: g=r>>4, s=h*2 (+1 at +256), rr=r&15
    int awb = (r >> 4) * 1024 + h * 512 + (r & 15) * 16;

    const char* bsrch = Whi + ((size_t)(nt * NKT) << 13) + tid * 16;
    const char* bsrcl = Wlo + ((size_t)(nt * NKT) << 13) + tid * 16;

    // fragment read offsets (within one parity buffer)
    int afro = (wv >> 1) * 4096 + kh * 256 + fr * 16;   // + f*1024
    int bfro = (wv & 1) * 4096 + kh * 256 + fr * 16;    // + f*1024

#define BSTG(ktn, p)                                                      \
    do {                                                                  \
        size_t tb = (size_t)(ktn) << 13;                                  \
        gload16(bsrch + tb,        lB + (p) * 16384 + tid * 16);          \
        gload16(bsrch + tb + 4096, lB + (p) * 16384 + 4096 + tid * 16);   \
        gload16(bsrcl + tb,        lB + (p) * 16384 + 8192 + tid * 16);   \
        gload16(bsrcl + tb + 4096, lB + (p) * 16384 + 12288 + tid * 16);  \
    } while (0)

#define ASPLIT(v0, v1, v2, v3, p)                                         \
    do {                                                                  \
        u16x8 h0, h1, l0, l1;                                             \
        split8(v0, v1, h0, l0);                                           \
        split8(v2, v3, h1, l1);                                           \
        *(u16x8*)(lA + (p) * 16384 + awb) = h0;                           \
        *(u16x8*)(lA + (p) * 16384 + awb + 256) = h1;                     \
        *(u16x8*)(lA + (p) * 16384 + 8192 + awb) = l0;                    \
        *(u16x8*)(lA + (p) * 16384 + 8192 + awb + 256) = l1;              \
    } while (0)

#define ALOAD(d0, d1, d2, d3, ktn)                                        \
    do {                                                                  \
        const float* ap = asrc + (size_t)(ktn) * 32;                      \
        d0 = ((const float4*)ap)[0];                                      \
        d1 = ((const float4*)ap)[1];                                      \
        d2 = ((const float4*)ap)[2];                                      \
        d3 = ((const float4*)ap)[3];                                      \
    } while (0)

#define FRAG_MFMA(p)                                                      \
    do {                                                                  \
        bf16x8 ah[4], al[4], bh[4], bl[4];                                \
        _Pragma("unroll") for (int f = 0; f < 4; ++f) {                   \
            ah[f] = *(const bf16x8*)(lA + (p) * 16384 + afro + f * 1024); \
            al[f] = *(const bf16x8*)(lA + (p) * 16384 + 8192 + afro + f * 1024); \
            bh[f] = *(const bf16x8*)(lB + (p) * 16384 + bfro + f * 1024); \
            bl[f] = *(const bf16x8*)(lB + (p) * 16384 + 8192 + bfro + f * 1024); \
        }                                                                 \
        _Pragma("unroll") for (int i = 0; i < 4; ++i)                     \
            _Pragma("unroll") for (int j = 0; j < 4; ++j) {               \
                acc[i][j] = __builtin_amdgcn_mfma_f32_16x16x32_bf16(ah[i], bh[j], acc[i][j], 0, 0, 0); \
                acc[i][j] = __builtin_amdgcn_mfma_f32_16x16x32_bf16(ah[i], bl[j], acc[i][j], 0, 0, 0); \
                acc[i][j] = __builtin_amdgcn_mfma_f32_16x16x32_bf16(al[i], bh[j], acc[i][j], 0, 0, 0); \
            }                                                             \
    } while (0)

    f32x4 acc[4][4] = {};
    float4 a00, a01, a02, a03, a10, a11, a12, a13;

    // prologue: Bbuf0 <- B(0); a0 <- A(0) -> Abuf0; a1 <- A(1)
    BSTG(0, 0);
    ALOAD(a00, a01, a02, a03, 0);
    ALOAD(a10, a11, a12, a13, 1);
    ASPLIT(a00, a01, a02, a03, 0);
    __syncthreads();

#pragma unroll 1
    for (int tt = 0; tt < 16; ++tt) {
        int t0 = 2 * tt;
        // step t0 (p=0): stage B(t0+1)->buf1, split a1=A(t0+1)->Abuf1,
        //                load A(t0+2)->a0, compute from buf0
        BSTG((t0 + 1) & 31, 1);
        ASPLIT(a10, a11, a12, a13, 1);
        ALOAD(a00, a01, a02, a03, (t0 + 2) & 31);
        FRAG_MFMA(0);
        __syncthreads();
        // step t0+1 (p=1): stage B(t0+2)->buf0, split a0=A(t0+2)->Abuf0,
        //                  load A(t0+3)->a1, compute from buf1
        BSTG((t0 + 2) & 31, 0);
        ASPLIT(a00, a01, a02, a03, 0);
        ALOAD(a10, a11, a12, a13, (t0 + 3) & 31);
        FRAG_MFMA(1);
        __syncthreads();
    }

    // ---- epilogue: bias + C write (same mapping as R4/R9) ----
    int wm = (wv >> 1) * 64, wn = (wv & 1) * 64;
    const float* bias = (nt < 2) ? bfv : btv;
    int nb0 = nt * 128 - ((nt < 2) ? 0 : 256);
#pragma unroll
    for (int j = 0; j < 4; ++j) {
        int ncol = nt * 128 + wn + j * 16 + fr;
        float bv = bias[nb0 + wn + j * 16 + fr];
#pragma unroll
        for (int i = 0; i < 4; ++i) {
            int mrow = mt * 128 + wm + i * 16 + kh * 4;
#pragma unroll
            for (int rr = 0; rr < 4; ++rr) {
                C[(size_t)(mrow + rr) * N_ + ncol] = acc[i][j][rr] + bv;
            }
        }
    }
#undef BSTG
#undef ASPLIT
#undef ALOAD
#undef FRAG_MFMA
}

// ---- gather + relu-dot: out[b][v] ----
__global__ __launch_bounds__(1024) void out_kernel(
    const float* __restrict__ C, const float* __restrict__ gp,
    const float* __restrict__ promo_tab, const float* __restrict__ Wsv,
    const float* __restrict__ bsv,
    const int* __restrict__ from_sqs, const int* __restrict__ to_sqs,
    const int* __restrict__ ptypes, float* __restrict__ out) {
    __shared__ float cb[NSQ * N_];       // 128 KB: fp|tp rows of this b
    __shared__ float gpl[ND];
    __shared__ float wsl[ND];
    __shared__ float pl[5 * ND];
    __shared__ int fsq[NV], tsq[NV], pty[NV];
    int b = blockIdx.x;
    int tid = threadIdx.x;
    const float4* src = (const float4*)(C + (size_t)b * NSQ * N_);
    float4* dst = (float4*)cb;
#pragma unroll
    for (int i = 0; i < 8; ++i) dst[tid + i * 1024] = src[tid + i * 1024];
    if (tid < 64) ((float4*)gpl)[tid] = ((const float4*)(gp + (size_t)b * ND))[tid];
    else if (tid < 128) ((float4*)wsl)[tid - 64] = ((const float4*)Wsv)[tid - 64];
    else if (tid < 448) ((float4*)pl)[tid - 128] = ((const float4*)promo_tab)[tid - 128];
    for (int v = tid; v < NV; v += 1024) {
        fsq[v] = from_sqs[v];
        tsq[v] = to_sqs[v];
        pty[v] = ptypes[v];
    }
    __syncthreads();

    int wave = tid >> 6, lane = tid & 63;
    float bias0 = bsv[0];
    const float4* cb4 = (const float4*)cb;
    const float4* gp4 = (const float4*)gpl;
    const float4* ws4 = (const float4*)wsl;
    const float4* pl4 = (const float4*)pl;
    for (int v = wave; v < NV; v += 16) {
        int sf = fsq[v];
        int st = tsq[v];
        int p  = pty[v];
        float4 a = cb4[sf * 128 + lane];
        float4 t = cb4[st * 128 + 64 + lane];
        float4 g = gp4[lane];
        float4 pp = pl4[p * 64 + lane];
        float4 w = ws4[lane];
        float c0 = a.x * t.x + g.x + pp.x;
        float c1 = a.y * t.y + g.y + pp.y;
        float c2 = a.z * t.z + g.z + pp.z;
        float c3 = a.w * t.w + g.w + pp.w;
        float s = fmaxf(c0, 0.f) * w.x + fmaxf(c1, 0.f) * w.y +
                  fmaxf(c2, 0.f) * w.z + fmaxf(c3, 0.f) * w.w;
#pragma unroll
        for (int o = 32; o > 0; o >>= 1) s += __shfl_xor(s, o, 64);
        if (lane == 0) out[(size_t)b * NV + v] = s + bias0;
    }
}

extern "C" void kernel_launch(void* const* d_in, const int* in_sizes, int n_in,
                              void* d_out, int out_size, void* d_ws, size_t ws_size,
                              hipStream_t stream) {
    (void)in_sizes; (void)n_in; (void)out_size; (void)ws_size;
    const float* hid   = (const float*)d_in[0];
    const float* Wf    = (const float*)d_in[1];
    const float* bfv   = (const float*)d_in[2];
    const float* Wt    = (const float*)d_in[3];
    const float* btv   = (const float*)d_in[4];
    const float* Wg    = (const float*)d_in[5];
    const float* bgv   = (const float*)d_in[6];
    const float* promo = (const float*)d_in[7];
    const float* Wsv   = (const float*)d_in[8];
    const float* bsv   = (const float*)d_in[9];
    const int* from_sqs = (const int*)d_in[10];
    const int* to_sqs   = (const int*)d_in[11];
    const int* ptypes   = (const int*)d_in[12];
    float* out = (float*)d_out;

    char* ws = (char*)d_ws;
    // layout: Whi 1MiB | Wlo 1MiB | C 32MiB | gp 256KiB
    char* Whi = ws;
    char* Wlo = ws + 1048576;
    float* C  = (float*)(ws + 2097152);
    float* gp = (float*)(ws + 35651584);

    cast_W_kernel<<<256, 256, 0, stream>>>(Wf, Wt, Whi, Wlo);
    gp_kernel<<<256, 1024, 0, stream>>>(hid, Wg, bgv, gp);
    gemm3f_kernel<<<512, 256, 0, stream>>>(hid, Whi, Wlo, bfv, btv, C);
    out_kernel<<<256, 1024, 0, stream>>>(C, gp, promo, Wsv, bsv,
                                         from_sqs, to_sqs, ptypes, out);
}